// Round 4
// baseline (755.001 us; speedup 1.0000x reference)
//
#include <hip/hip_runtime.h>
#include <hip/hip_bf16.h>
#include <stdint.h>

// ENAS LSTM controller. R4: SAME structure as R3 (one 1024-thread workgroup
// per sampler block, all state in LDS/registers, 48B of d_ws), but ALL I/O is
// FLOAT32 per the reference (R1-R3 read f32 tensors as bf16 -> low mantissa
// halfwords decode as NaN-patterned bf16 weights -> NaN c/h; and 2-byte
// stores at bf16 offsets landed inside Output 0's float32 window -> the
// observed NaN). JAX threefry PRNG bit-exact (partitionable random-bits
// path: bits32 = x0 ^ x1).

#define NBLK  6
#define NTHR  1024
#define TINYF 1.17549435e-38f
#define XS_ENC (-1)

struct U2 { uint32_t x, y; };

// Threefry-2x32, 20 rounds (Random123 / JAX). Key (k0,k1), counter (c0,c1).
__device__ __forceinline__ U2 tf2x32(uint32_t k0, uint32_t k1,
                                     uint32_t c0, uint32_t c1) {
  uint32_t ks2 = k0 ^ k1 ^ 0x1BD11BDAu;
  uint32_t x0 = c0 + k0, x1 = c1 + k1;
#define TFR(r) { x0 += x1; x1 = (x1 << (r)) | (x1 >> (32 - (r))); x1 ^= x0; }
  TFR(13) TFR(15) TFR(26) TFR(6)   x0 += k1;  x1 += ks2 + 1u;
  TFR(17) TFR(29) TFR(16) TFR(24)  x0 += ks2; x1 += k0 + 2u;
  TFR(13) TFR(15) TFR(26) TFR(6)   x0 += k0;  x1 += k1 + 3u;
  TFR(17) TFR(29) TFR(16) TFR(24)  x0 += k1;  x1 += ks2 + 4u;
  TFR(13) TFR(15) TFR(26) TFR(6)   x0 += ks2; x1 += k0 + 5u;
#undef TFR
  U2 r; r.x = x0; r.y = x1; return r;
}

__device__ __forceinline__ float sigf(float x) {
  return 1.0f / (1.0f + expf(-x));
}

__global__ __launch_bounds__(NTHR, 1) void ctrl_kernel(
    const float* __restrict__ enc_w,
    const float* __restrict__ wih,
    const float* __restrict__ whh,
    const float* __restrict__ b_ih,
    const float* __restrict__ b_hh,
    const float* __restrict__ w1,
    const float* __restrict__ w2,
    const float* __restrict__ vvec,
    float* __restrict__ part,          // 12 floats in d_ws
    float* __restrict__ out) {

  const int b = blockIdx.x;
  const int tid = threadIdx.x;

  __shared__ __align__(16) float hL[256], encL[256], vL[256], w2hL[256];
  __shared__ __align__(16) float biasL[1024], partL[1024];
  __shared__ __align__(16) float aw1L[7][256];
  __shared__ __align__(16) float anchL[7][256];
  __shared__ float logitL[8];
  __shared__ int   selL;

  // ---- preload constants into LDS ----
  if (tid < 256) {
    encL[tid] = enc_w[tid];   // encoder(0) = enc_w row 0
    vL[tid]   = vvec[tid];
  }
  biasL[tid] = b_ih[tid] + b_hh[tid];
  __syncthreads();

  // 256-wide dot of row-major f32 weight row with an LDS fp32 vector.
  auto rowdot = [&](const float* W, const float* xp, int row) {
    const float4* wp = (const float4*)(W + row * 256);
    float acc = 0.0f;
    #pragma unroll 8
    for (int kb = 0; kb < 64; ++kb) {
      float4 w = wp[kb];
      float4 x = *(const float4*)(xp + kb * 4);
      acc += w.x * x.x + w.y * x.y + w.z * x.z + w.w * x.w;
    }
    return acc;
  };

  // 64-wide quarter-dot (256x256 GEMVs split 4 ways across 1024 threads).
  auto qdot = [&](const float* W, const float* xp, int row, int q) {
    const float4* wp = (const float4*)(W + row * 256 + q * 64);
    float acc = 0.0f;
    #pragma unroll
    for (int kb = 0; kb < 16; ++kb) {
      float4 w = wp[kb];
      float4 x = *(const float4*)(xp + q * 64 + kb * 4);
      acc += w.x * x.x + w.y * x.y + w.z * x.z + w.w * x.w;
    }
    return acc;
  };

  // wih @ enc is reused by every enc-input cell: compute once per thread.
  const float encih = rowdot(wih, encL, tid);

  float cv = 0.0f;                            // c for element tid (tid<256)
  U2 bk = tf2x32(0u, 42u, 0u, (uint32_t)b);   // fold_in(key(42), b)
  int step = 0;
  float lpAcc = 0.0f, entAcc = 0.0f;

  // One LSTM cell. xsel: XS_ENC = enc0, 0/1 = zero anchors (x-term skipped),
  // >=2 = real anchor h. hzero: h,c are zeros (first cell).
  auto do_cell = [&](int xsel, bool hzero, bool isAnchor, int aid) {
    float acc = 0.0f;
    if (xsel == XS_ENC)      acc = encih;
    else if (xsel >= 2)      acc = rowdot(wih, anchL[xsel], tid);
    if (!hzero)              acc += rowdot(whh, hL, tid);
    partL[tid] = acc;
    __syncthreads();
    if (tid < 256) {
      float gi = partL[tid]         + biasL[tid];
      float gf = partL[256 + tid]   + biasL[256 + tid];
      float gg = partL[512 + tid]   + biasL[512 + tid];
      float go = partL[768 + tid]   + biasL[768 + tid];
      float c2 = sigf(gf) * cv + sigf(gi) * tanhf(gg);
      float h2 = sigf(go) * tanhf(c2);
      cv = c2;
      hL[tid] = h2;
      if (isAnchor) anchL[aid][tid] = h2;
    }
    __syncthreads();
  };

  auto do_aw1 = [&](int aid) {   // anchors_w1[aid] = w1 @ h
    int q = tid >> 8, r = tid & 255;
    partL[tid] = qdot(w1, hL, r, q);
    __syncthreads();
    if (tid < 256)
      aw1L[aid][tid] = partL[tid] + partL[256 + tid] +
                       partL[512 + tid] + partL[768 + tid];
    __syncthreads();
  };

  auto do_sample = [&](int L) -> int {
    int q = tid >> 8, r = tid & 255;
    partL[tid] = qdot(w2, hL, r, q);
    __syncthreads();
    if (tid < 256)
      w2hL[tid] = partL[tid] + partL[256 + tid] +
                  partL[512 + tid] + partL[768 + tid];
    __syncthreads();
    int wv = tid >> 6, lane = tid & 63;
    if (wv < L) {                      // wave wv computes logit wv
      float acc = 0.0f;
      #pragma unroll
      for (int j = 0; j < 4; ++j) {
        int k = lane * 4 + j;
        acc += tanhf(aw1L[wv][k] + w2hL[k]) * vL[k];
      }
      acc += __shfl_down(acc, 32);
      acc += __shfl_down(acc, 16);
      acc += __shfl_down(acc, 8);
      acc += __shfl_down(acc, 4);
      acc += __shfl_down(acc, 2);
      acc += __shfl_down(acc, 1);
      if (lane == 0) logitL[wv] = acc;
    }
    __syncthreads();
    if (tid == 0) {
      float lg[6];
      for (int i = 0; i < L; ++i) lg[i] = 1.1f * tanhf(logitL[i] / 5.0f);
      // skey = fold_in(bkey, step); gumbel bits: partitionable threefry path
      U2 sk = tf2x32(bk.x, bk.y, 0u, (uint32_t)step);
      float best = 0.0f; int bi = 0;
      for (int i = 0; i < L; ++i) {
        U2 r2 = tf2x32(sk.x, sk.y, 0u, (uint32_t)i);
        uint32_t bits = r2.x ^ r2.y;
        float u = __uint_as_float((bits >> 9) | 0x3f800000u) - 1.0f;
        u = fmaxf(TINYF, u + TINYF);   // jax uniform(minval=tiny, maxval=1)
        float gum = -logf(-logf(u));
        float s = lg[i] + gum;
        if (i == 0 || s > best) { best = s; bi = i; }  // first-max = argmax
      }
      float mx = lg[0];
      for (int i = 1; i < L; ++i) mx = fmaxf(mx, lg[i]);
      float se = 0.0f;
      for (int i = 0; i < L; ++i) se += expf(lg[i] - mx);
      float lse = logf(se);
      lpAcc += -(lg[bi] - mx - lse);
      float es = 0.0f;
      for (int i = 0; i < L; ++i) {
        float l = lg[i] - mx - lse;
        es += l * expf(l);
      }
      entAcc += -es;
      selL = bi;
      out[b * 10 + step] = (float)bi;
    }
    __syncthreads();
    step++;
    return selL;
  };

  // ---- chain ----
  // Reference runs the zero-state cell twice with identical inputs -> once;
  // anchors[0]=anchors[1]=zeros, anchors_w1[0]=anchors_w1[1]=w1@h1.
  do_cell(XS_ENC, true, false, 0);
  do_aw1(0);
  if (tid < 256) aw1L[1][tid] = aw1L[0][tid];
  __syncthreads();

  for (int L = 2; L <= 6; ++L) {
    do_cell(XS_ENC, false, false, 0);
    int s1 = do_sample(L);
    do_cell(s1, false, false, 0);
    int s2 = do_sample(L);
    do_cell(s2, false, L < 6, L);   // anchor cell (anchor/aw1 unused at L=6)
    if (L < 6) do_aw1(L);
  }

  // outputs (all f32): arcs[0..59]; lp@60, ent@61 via part+fin_kernel;
  // c@62..317, h@318..573 from the last block's final state.
  if (b == NBLK - 1 && tid < 256) {
    out[62 + tid]  = cv;
    out[318 + tid] = hL[tid];
  }
  if (tid == 0) {
    part[2 * b]     = lpAcc;
    part[2 * b + 1] = entAcc;
  }
}

__global__ void fin_kernel(const float* __restrict__ part,
                           float* __restrict__ out) {
  float lp = 0.0f, en = 0.0f;
  for (int b = 0; b < NBLK; ++b) { lp += part[2 * b]; en += part[2 * b + 1]; }
  out[60] = lp;
  out[61] = en;
}

extern "C" void kernel_launch(void* const* d_in, const int* in_sizes, int n_in,
                              void* d_out, int out_size, void* d_ws, size_t ws_size,
                              hipStream_t stream) {
  const float* enc = (const float*)d_in[0];
  const float* wih = (const float*)d_in[1];
  const float* whh = (const float*)d_in[2];
  const float* bih = (const float*)d_in[3];
  const float* bhh = (const float*)d_in[4];
  const float* w1  = (const float*)d_in[5];
  const float* w2  = (const float*)d_in[6];
  const float* v   = (const float*)d_in[7];
  float* part = (float*)d_ws;                       // 48 bytes only
  float* out = (float*)d_out;

  ctrl_kernel<<<dim3(NBLK), dim3(NTHR), 0, stream>>>(
      enc, wih, whh, bih, bhh, w1, w2, v, part, out);
  fin_kernel<<<dim3(1), dim3(1), 0, stream>>>(part, out);
}

// Round 5
// 220.883 us; speedup vs baseline: 3.4181x; 3.4181x over previous
//
#include <hip/hip_runtime.h>
#include <hip/hip_bf16.h>
#include <stdint.h>

// ENAS LSTM controller. R5: distribute each of the 6 independent chains over
// P=8 workgroups (48 wgs total, 1024 thr each). Weights live in VGPRs for the
// whole kernel (each thread owns a disjoint 32-float slice of wih/whh rows and
// an 8-float slice of w1/w2 rows) -> GEMVs are pure FMA, no weight refetch.
// Cross-wg handoff (h, logit partials) via agent-scope atomics + per-block
// monotonic-phase spin barrier (25 barriers/chain). Sampling lane-parallel on
// wave 0. PRNG identical to the bit-exact R4. Fallback to the proven R4
// single-wg kernel if ws_size is too small for the 45KB fast-path scratch.

#define NBLK  6
#define PWG   8
#define TINYF 1.17549435e-38f
#define XS_ENC (-1)

// fast-path ws layout (bytes)
#define OFF_BAR  0u          // int[NBLK][16]  (count@0, release@1, 64B apart)
#define OFF_LPG  384u        // float[NBLK][64] logit partials (i*8+p, i<6)
#define OFF_HG   1920u       // float[2][NBLK][256] double-buffered h
#define OFF_ANCH 14208u      // float[NBLK][5][256] anchors (slots for aid 2..6)
#define OFF_PART 44928u      // float[12] lp/ent partials
#define WS_NEED  44976u

struct U2 { uint32_t x, y; };

// Threefry-2x32, 20 rounds (Random123 / JAX). Key (k0,k1), counter (c0,c1).
__device__ __forceinline__ U2 tf2x32(uint32_t k0, uint32_t k1,
                                     uint32_t c0, uint32_t c1) {
  uint32_t ks2 = k0 ^ k1 ^ 0x1BD11BDAu;
  uint32_t x0 = c0 + k0, x1 = c1 + k1;
#define TFR(r) { x0 += x1; x1 = (x1 << (r)) | (x1 >> (32 - (r))); x1 ^= x0; }
  TFR(13) TFR(15) TFR(26) TFR(6)   x0 += k1;  x1 += ks2 + 1u;
  TFR(17) TFR(29) TFR(16) TFR(24)  x0 += ks2; x1 += k0 + 2u;
  TFR(13) TFR(15) TFR(26) TFR(6)   x0 += k0;  x1 += k1 + 3u;
  TFR(17) TFR(29) TFR(16) TFR(24)  x0 += k1;  x1 += ks2 + 4u;
  TFR(13) TFR(15) TFR(26) TFR(6)   x0 += ks2; x1 += k0 + 5u;
#undef TFR
  U2 r; r.x = x0; r.y = x1; return r;
}

__device__ __forceinline__ float sigf(float x) {
  return 1.0f / (1.0f + expf(-x));
}
__device__ __forceinline__ void gstore(float* p, float v) {
  __hip_atomic_store(p, v, __ATOMIC_RELAXED, __HIP_MEMORY_SCOPE_AGENT);
}
__device__ __forceinline__ float gload(const float* p) {
  return __hip_atomic_load(p, __ATOMIC_RELAXED, __HIP_MEMORY_SCOPE_AGENT);
}

__global__ void init_kernel(unsigned char* __restrict__ ws) {
  int t = threadIdx.x;
  if (t < NBLK * 16) ((int*)(ws + OFF_BAR))[t] = 0;
}

// ---------------- fast path: 8 wgs per block, register-resident weights ----
__global__ __launch_bounds__(1024) void ctrl_fast(
    const float* __restrict__ enc_w,
    const float* __restrict__ wih,
    const float* __restrict__ whh,
    const float* __restrict__ b_ih,
    const float* __restrict__ b_hh,
    const float* __restrict__ w1,
    const float* __restrict__ w2,
    const float* __restrict__ vvec,
    unsigned char* __restrict__ ws,
    float* __restrict__ out) {

  const int wg = blockIdx.x;
  const int b = wg >> 3, p = wg & 7;
  const int tid = threadIdx.x;

  // 1024-row GEMV decomposition: 128 local rows x 8 k-slices of 32
  const int rl = tid >> 3, s = tid & 7;
  const int g = rl >> 5, el = rl & 31;
  const int row = g * 256 + p * 32 + el;
  const int k0 = s * 32;
  // 256-row GEMV decomposition: 32 local rows x 32 k-slices of 8
  const int rl2 = tid >> 5, s2 = tid & 31;
  const int row2 = p * 32 + rl2;
  const int k02 = s2 * 8;
  const int t4 = s2 >> 2;          // LDS rotation for conflict-free reads

  int*   bar  = (int*)(ws + OFF_BAR) + b * 16;
  float* lpg  = (float*)(ws + OFF_LPG) + b * 64;
  float* hg   = (float*)(ws + OFF_HG);
  float* anch = (float*)(ws + OFF_ANCH);
  float* part = (float*)(ws + OFF_PART);

  __shared__ __align__(16) float hL[256], xL[256], encL[256];
  __shared__ __align__(16) float partL[1024];
  __shared__ __align__(16) float rowSumL[128];
  __shared__ float vS[32], biasS[128], w2hS[32];
  __shared__ float aw1S[7][32];
  __shared__ float logitPGL[48];
  __shared__ int   selL;

  if (tid < 256) encL[tid] = enc_w[tid];
  if (tid < 32)  vS[tid] = vvec[p * 32 + tid];
  if (tid < 128) {
    int gg = tid >> 5, ee = tid & 31, r = gg * 256 + p * 32 + ee;
    biasS[tid] = b_ih[r] + b_hh[r];
  }

  // ---- register-resident weight slices (rotated chunk order so LDS x reads
  // are conflict-free: s-group c reads chunk (c+s)&7) ----
  float4 wihr[8], whhr[8];
  #pragma unroll
  for (int c = 0; c < 8; ++c) {
    int cc = (c + s) & 7;
    wihr[c] = *(const float4*)(wih + row * 256 + k0 + cc * 4);
    whhr[c] = *(const float4*)(whh + row * 256 + k0 + cc * 4);
  }
  float w1r[8], w2r[8];
  #pragma unroll
  for (int j = 0; j < 8; ++j) {
    int jj = (j + t4) & 7;
    w1r[j] = w1[row2 * 256 + k02 + jj];
    w2r[j] = w2[row2 * 256 + k02 + jj];
  }
  __syncthreads();

  auto dotIH = [&](const float* x) {
    float acc = 0.0f;
    #pragma unroll
    for (int c = 0; c < 8; ++c) {
      int cc = (c + s) & 7;
      float4 xv = *(const float4*)(x + k0 + cc * 4);
      float4 w = wihr[c];
      acc += w.x * xv.x + w.y * xv.y + w.z * xv.z + w.w * xv.w;
    }
    return acc;
  };
  auto dotHH = [&]() {
    float acc = 0.0f;
    #pragma unroll
    for (int c = 0; c < 8; ++c) {
      int cc = (c + s) & 7;
      float4 xv = *(const float4*)(hL + k0 + cc * 4);
      float4 w = whhr[c];
      acc += w.x * xv.x + w.y * xv.y + w.z * xv.z + w.w * xv.w;
    }
    return acc;
  };
  auto dotW1 = [&]() {
    float acc = 0.0f;
    #pragma unroll
    for (int j = 0; j < 8; ++j) acc += w1r[j] * hL[k02 + ((j + t4) & 7)];
    return acc;
  };
  auto dotW2 = [&]() {
    float acc = 0.0f;
    #pragma unroll
    for (int j = 0; j < 8; ++j) acc += w2r[j] * hL[k02 + ((j + t4) & 7)];
    return acc;
  };

  const float encih = dotIH(encL);   // wih @ enc, reused by all enc cells

  float cv = 0.0f;                            // c for element p*32+tid (tid<32)
  U2 bk = tf2x32(0u, 42u, 0u, (uint32_t)b);   // fold_in(key(42), b)
  int phase = 0, wpar = 0, step = 0;
  float lpAcc = 0.0f, entAcc = 0.0f;

  auto barrier8 = [&]() {
    __syncthreads();
    phase++;
    if (tid == 0) {
      int old = __hip_atomic_fetch_add(&bar[0], 1, __ATOMIC_ACQ_REL,
                                       __HIP_MEMORY_SCOPE_AGENT);
      if (old == phase * PWG - 1) {
        __hip_atomic_store(&bar[1], phase, __ATOMIC_RELEASE,
                           __HIP_MEMORY_SCOPE_AGENT);
      } else {
        int cur;
        do {
          __builtin_amdgcn_s_sleep(2);
          cur = __hip_atomic_load(&bar[1], __ATOMIC_ACQUIRE,
                                  __HIP_MEMORY_SCOPE_AGENT);
        } while (cur < phase);
      }
    }
    __syncthreads();
  };

  // acc -> gates -> c,h update; broadcast h via global; barrier; restage hL.
  auto cellUpdate = [&](float acc, bool isAnchor, int aid, bool lastCell) {
    partL[tid] = acc;
    __syncthreads();
    if (tid < 128) {
      float ssum = 0.0f;
      #pragma unroll
      for (int j = 0; j < 8; ++j) ssum += partL[tid * 8 + j];
      rowSumL[tid] = ssum + biasS[tid];
    }
    __syncthreads();
    if (tid < 32) {
      float gi = rowSumL[tid],      gf = rowSumL[32 + tid];
      float gg2 = rowSumL[64 + tid], go = rowSumL[96 + tid];
      float c2 = sigf(gf) * cv + sigf(gi) * tanhf(gg2);
      float h2 = sigf(go) * tanhf(c2);
      cv = c2;
      int e = p * 32 + tid;
      if (!lastCell) gstore(&hg[wpar * (NBLK * 256) + b * 256 + e], h2);
      if (isAnchor)  gstore(&anch[(b * 5 + aid) * 256 + e], h2);
      if (lastCell && b == NBLK - 1) { out[62 + e] = cv; out[318 + e] = h2; }
    }
    if (!lastCell) {
      barrier8();
      if (tid < 256) hL[tid] = gload(&hg[wpar * (NBLK * 256) + b * 256 + tid]);
      wpar ^= 1;
      __syncthreads();
    }
  };

  auto doAw1 = [&](int aid) {      // local 32-slice of w1 @ h, stays in LDS
    float a1 = dotW1();
    a1 += __shfl_down(a1, 16, 32);
    a1 += __shfl_down(a1, 8, 32);
    a1 += __shfl_down(a1, 4, 32);
    a1 += __shfl_down(a1, 2, 32);
    a1 += __shfl_down(a1, 1, 32);
    if (s2 == 0) aw1S[aid][rl2] = a1;
    __syncthreads();
  };

  auto doSample = [&](int L) -> int {
    // local 32-slice of w2 @ h
    float a2 = dotW2();
    a2 += __shfl_down(a2, 16, 32);
    a2 += __shfl_down(a2, 8, 32);
    a2 += __shfl_down(a2, 4, 32);
    a2 += __shfl_down(a2, 2, 32);
    a2 += __shfl_down(a2, 1, 32);
    if (s2 == 0) w2hS[rl2] = a2;
    __syncthreads();
    // logit partials over this wg's k-slice: wave i handles logit i
    int wv = tid >> 6, lane = tid & 63;
    if (wv < L && lane < 32) {
      float t = tanhf(aw1S[wv][lane] + w2hS[lane]) * vS[lane];
      t += __shfl_down(t, 16, 32);
      t += __shfl_down(t, 8, 32);
      t += __shfl_down(t, 4, 32);
      t += __shfl_down(t, 2, 32);
      t += __shfl_down(t, 1, 32);
      if (lane == 0) gstore(&lpg[wv * 8 + p], t);
    }
    barrier8();
    if (tid < 8 * L) logitPGL[tid] = gload(&lpg[tid]);
    __syncthreads();
    if (tid < 64) {                 // wave 0: lane-parallel selection
      float lg = 0.0f, sgum = -1e30f;
      if (tid < L) {
        float ls = 0.0f;
        for (int j = 0; j < 8; ++j) ls += logitPGL[tid * 8 + j];
        lg = 1.1f * tanhf(ls * 0.2f);
        U2 sk = tf2x32(bk.x, bk.y, 0u, (uint32_t)step);
        U2 r2 = tf2x32(sk.x, sk.y, 0u, (uint32_t)tid);
        uint32_t bits = r2.x ^ r2.y;
        float u = __uint_as_float((bits >> 9) | 0x3f800000u) - 1.0f;
        u = fmaxf(TINYF, u + TINYF);
        sgum = lg - logf(-logf(u));
      }
      int bi = 0;
      float best = __shfl(sgum, 0, 64);
      for (int j = 1; j < L; ++j) {
        float sj = __shfl(sgum, j, 64);
        if (sj > best) { best = sj; bi = j; }   // first-max = jnp.argmax
      }
      float mx = __shfl(lg, 0, 64);
      for (int j = 1; j < L; ++j) mx = fmaxf(mx, __shfl(lg, j, 64));
      float se = 0.0f;
      for (int j = 0; j < L; ++j) se += expf(__shfl(lg, j, 64) - mx);
      float lse = logf(se);
      float lgbi = __shfl(lg, bi, 64);
      float es = 0.0f;
      for (int j = 0; j < L; ++j) {
        float l = __shfl(lg, j, 64) - mx - lse;
        es += l * expf(l);
      }
      if (tid == 0) {
        lpAcc += -(lgbi - mx - lse);
        entAcc += -es;
        selL = bi;
        if (p == 0) out[b * 10 + step] = (float)bi;
      }
    }
    __syncthreads();
    step++;
    int sel = selL;
    if (sel >= 2) {                 // stage chosen anchor as next x
      if (tid < 256) xL[tid] = gload(&anch[(b * 5 + sel - 2) * 256 + tid]);
      __syncthreads();
    }
    return sel;
  };

  // ---- chain ----
  cellUpdate(encih, false, 0, false);           // zero-state cell (run once)
  doAw1(0);
  if (tid < 32) aw1S[1][tid] = aw1S[0][tid];
  __syncthreads();

  for (int L = 2; L <= 6; ++L) {
    cellUpdate(encih + dotHH(), false, 0, false);
    int s1v = doSample(L);
    {
      float acc = (s1v >= 2) ? dotIH(xL) : 0.0f;
      cellUpdate(acc + dotHH(), false, 0, false);
    }
    int s2v = doSample(L);
    {
      float acc = (s2v >= 2) ? dotIH(xL) : 0.0f;
      cellUpdate(acc + dotHH(), L < 6, L - 2, L == 6);
    }
    if (L < 6) doAw1(L);
  }

  if (tid == 0 && p == 0) {
    part[2 * b]     = lpAcc;
    part[2 * b + 1] = entAcc;
  }
}

// ---------------- slow fallback: R4's proven single-wg kernel --------------
__global__ __launch_bounds__(1024, 1) void ctrl_slow(
    const float* __restrict__ enc_w,
    const float* __restrict__ wih,
    const float* __restrict__ whh,
    const float* __restrict__ b_ih,
    const float* __restrict__ b_hh,
    const float* __restrict__ w1,
    const float* __restrict__ w2,
    const float* __restrict__ vvec,
    float* __restrict__ part,
    float* __restrict__ out) {

  const int b = blockIdx.x;
  const int tid = threadIdx.x;

  __shared__ __align__(16) float hL[256], encL[256], vL[256], w2hL[256];
  __shared__ __align__(16) float biasL[1024], partL[1024];
  __shared__ __align__(16) float aw1L[7][256];
  __shared__ __align__(16) float anchL[7][256];
  __shared__ float logitL[8];
  __shared__ int   selL;

  if (tid < 256) { encL[tid] = enc_w[tid]; vL[tid] = vvec[tid]; }
  biasL[tid] = b_ih[tid] + b_hh[tid];
  __syncthreads();

  auto rowdot = [&](const float* W, const float* xp, int row) {
    const float4* wp = (const float4*)(W + row * 256);
    float acc = 0.0f;
    #pragma unroll 8
    for (int kb = 0; kb < 64; ++kb) {
      float4 w = wp[kb];
      float4 x = *(const float4*)(xp + kb * 4);
      acc += w.x * x.x + w.y * x.y + w.z * x.z + w.w * x.w;
    }
    return acc;
  };
  auto qdot = [&](const float* W, const float* xp, int row, int q) {
    const float4* wp = (const float4*)(W + row * 256 + q * 64);
    float acc = 0.0f;
    #pragma unroll
    for (int kb = 0; kb < 16; ++kb) {
      float4 w = wp[kb];
      float4 x = *(const float4*)(xp + q * 64 + kb * 4);
      acc += w.x * x.x + w.y * x.y + w.z * x.z + w.w * x.w;
    }
    return acc;
  };

  const float encih = rowdot(wih, encL, tid);
  float cv = 0.0f;
  U2 bk = tf2x32(0u, 42u, 0u, (uint32_t)b);
  int step = 0;
  float lpAcc = 0.0f, entAcc = 0.0f;

  auto do_cell = [&](int xsel, bool hzero, bool isAnchor, int aid) {
    float acc = 0.0f;
    if (xsel == XS_ENC)      acc = encih;
    else if (xsel >= 2)      acc = rowdot(wih, anchL[xsel], tid);
    if (!hzero)              acc += rowdot(whh, hL, tid);
    partL[tid] = acc;
    __syncthreads();
    if (tid < 256) {
      float gi = partL[tid]       + biasL[tid];
      float gf = partL[256 + tid] + biasL[256 + tid];
      float gg = partL[512 + tid] + biasL[512 + tid];
      float go = partL[768 + tid] + biasL[768 + tid];
      float c2 = sigf(gf) * cv + sigf(gi) * tanhf(gg);
      float h2 = sigf(go) * tanhf(c2);
      cv = c2; hL[tid] = h2;
      if (isAnchor) anchL[aid][tid] = h2;
    }
    __syncthreads();
  };
  auto do_aw1 = [&](int aid) {
    int q = tid >> 8, r = tid & 255;
    partL[tid] = qdot(w1, hL, r, q);
    __syncthreads();
    if (tid < 256)
      aw1L[aid][tid] = partL[tid] + partL[256 + tid] +
                       partL[512 + tid] + partL[768 + tid];
    __syncthreads();
  };
  auto do_sample = [&](int L) -> int {
    int q = tid >> 8, r = tid & 255;
    partL[tid] = qdot(w2, hL, r, q);
    __syncthreads();
    if (tid < 256)
      w2hL[tid] = partL[tid] + partL[256 + tid] +
                  partL[512 + tid] + partL[768 + tid];
    __syncthreads();
    int wv = tid >> 6, lane = tid & 63;
    if (wv < L) {
      float acc = 0.0f;
      #pragma unroll
      for (int j = 0; j < 4; ++j) {
        int k = lane * 4 + j;
        acc += tanhf(aw1L[wv][k] + w2hL[k]) * vL[k];
      }
      acc += __shfl_down(acc, 32);
      acc += __shfl_down(acc, 16);
      acc += __shfl_down(acc, 8);
      acc += __shfl_down(acc, 4);
      acc += __shfl_down(acc, 2);
      acc += __shfl_down(acc, 1);
      if (lane == 0) logitL[wv] = acc;
    }
    __syncthreads();
    if (tid == 0) {
      float lg[6];
      for (int i = 0; i < L; ++i) lg[i] = 1.1f * tanhf(logitL[i] / 5.0f);
      U2 sk = tf2x32(bk.x, bk.y, 0u, (uint32_t)step);
      float best = 0.0f; int bi = 0;
      for (int i = 0; i < L; ++i) {
        U2 r2 = tf2x32(sk.x, sk.y, 0u, (uint32_t)i);
        uint32_t bits = r2.x ^ r2.y;
        float u = __uint_as_float((bits >> 9) | 0x3f800000u) - 1.0f;
        u = fmaxf(TINYF, u + TINYF);
        float gum = -logf(-logf(u));
        float sgm = lg[i] + gum;
        if (i == 0 || sgm > best) { best = sgm; bi = i; }
      }
      float mx = lg[0];
      for (int i = 1; i < L; ++i) mx = fmaxf(mx, lg[i]);
      float se = 0.0f;
      for (int i = 0; i < L; ++i) se += expf(lg[i] - mx);
      float lse = logf(se);
      lpAcc += -(lg[bi] - mx - lse);
      float es = 0.0f;
      for (int i = 0; i < L; ++i) {
        float l = lg[i] - mx - lse;
        es += l * expf(l);
      }
      entAcc += -es;
      selL = bi;
      out[b * 10 + step] = (float)bi;
    }
    __syncthreads();
    step++;
    return selL;
  };

  do_cell(XS_ENC, true, false, 0);
  do_aw1(0);
  if (tid < 256) aw1L[1][tid] = aw1L[0][tid];
  __syncthreads();
  for (int L = 2; L <= 6; ++L) {
    do_cell(XS_ENC, false, false, 0);
    int s1 = do_sample(L);
    do_cell(s1, false, false, 0);
    int s2 = do_sample(L);
    do_cell(s2, false, L < 6, L);
    if (L < 6) do_aw1(L);
  }
  if (b == NBLK - 1 && tid < 256) {
    out[62 + tid]  = cv;
    out[318 + tid] = hL[tid];
  }
  if (tid == 0) { part[2 * b] = lpAcc; part[2 * b + 1] = entAcc; }
}

__global__ void fin_kernel(const float* __restrict__ part,
                           float* __restrict__ out) {
  float lp = 0.0f, en = 0.0f;
  for (int b = 0; b < NBLK; ++b) { lp += part[2 * b]; en += part[2 * b + 1]; }
  out[60] = lp;
  out[61] = en;
}

extern "C" void kernel_launch(void* const* d_in, const int* in_sizes, int n_in,
                              void* d_out, int out_size, void* d_ws, size_t ws_size,
                              hipStream_t stream) {
  const float* enc = (const float*)d_in[0];
  const float* wih = (const float*)d_in[1];
  const float* whh = (const float*)d_in[2];
  const float* bih = (const float*)d_in[3];
  const float* bhh = (const float*)d_in[4];
  const float* w1  = (const float*)d_in[5];
  const float* w2  = (const float*)d_in[6];
  const float* v   = (const float*)d_in[7];
  unsigned char* ws = (unsigned char*)d_ws;
  float* out = (float*)d_out;

  if (ws_size >= WS_NEED) {
    float* part = (float*)(ws + OFF_PART);
    init_kernel<<<dim3(1), dim3(128), 0, stream>>>(ws);
    ctrl_fast<<<dim3(NBLK * PWG), dim3(1024), 0, stream>>>(
        enc, wih, whh, bih, bhh, w1, w2, v, ws, out);
    fin_kernel<<<dim3(1), dim3(1), 0, stream>>>(part, out);
  } else {
    float* part = (float*)ws;   // 48 bytes
    ctrl_slow<<<dim3(NBLK), dim3(1024), 0, stream>>>(
        enc, wih, whh, bih, bhh, w1, w2, v, part, out);
    fin_kernel<<<dim3(1), dim3(1), 0, stream>>>(part, out);
  }
}

// Round 6
// 190.171 us; speedup vs baseline: 3.9701x; 1.1615x over previous
//
#include <hip/hip_runtime.h>
#include <stdint.h>

// ENAS LSTM controller. R6: single fused kernel (no init/fin launches).
// 6 chains x 8 wgs (grid 64, b = blockIdx&7 XCD swizzle, b>=6 exit).
// Weights VGPR-resident as in R5. Cross-wg sync via flag-array barrier
// (per-wg slot, release-store phase / parallel acquire-poll) -- removes the
// serialized fetch_add arrivals of R5. Anchors kept in per-wg LDS (each wg
// reconstructs full h every cell, so anchor copies are local) -- removes all
// global anchor traffic. Init: per-chain ready-magic handshake; final lp/ent
// reduction: done-magic flags spun on by block (5,0). ws usage 14.5KB.
// Math identical to bit-exact R5 (absmax 0).

#define NBLK  6
#define PWG   8
#define TINYF 1.17549435e-38f

#define OFF_BAR   0u      // int[8][16]: per-chain 8 slots (64B-spaced chains)
#define OFF_READY 512u    // int[8] ready magic
#define OFF_DONE  544u    // int[8] done magic
#define OFF_PART  576u    // float[16] lp/ent per chain
#define OFF_LPG   640u    // float[6][64] logit partials
#define OFF_HG    2176u   // float[2][6][256] double-buffered h
#define WS_NEED   14464u

#define READY_MAGIC 0x52454459
#define DONE_MAGIC  0x444f4e45

struct U2 { uint32_t x, y; };

// Threefry-2x32, 20 rounds (Random123 / JAX). Key (k0,k1), counter (c0,c1).
__device__ __forceinline__ U2 tf2x32(uint32_t k0, uint32_t k1,
                                     uint32_t c0, uint32_t c1) {
  uint32_t ks2 = k0 ^ k1 ^ 0x1BD11BDAu;
  uint32_t x0 = c0 + k0, x1 = c1 + k1;
#define TFR(r) { x0 += x1; x1 = (x1 << (r)) | (x1 >> (32 - (r))); x1 ^= x0; }
  TFR(13) TFR(15) TFR(26) TFR(6)   x0 += k1;  x1 += ks2 + 1u;
  TFR(17) TFR(29) TFR(16) TFR(24)  x0 += ks2; x1 += k0 + 2u;
  TFR(13) TFR(15) TFR(26) TFR(6)   x0 += k0;  x1 += k1 + 3u;
  TFR(17) TFR(29) TFR(16) TFR(24)  x0 += k1;  x1 += ks2 + 4u;
  TFR(13) TFR(15) TFR(26) TFR(6)   x0 += ks2; x1 += k0 + 5u;
#undef TFR
  U2 r; r.x = x0; r.y = x1; return r;
}

__device__ __forceinline__ float sigf(float x) {
  return 1.0f / (1.0f + expf(-x));
}
__device__ __forceinline__ void gstore(float* p, float v) {
  __hip_atomic_store(p, v, __ATOMIC_RELAXED, __HIP_MEMORY_SCOPE_AGENT);
}
__device__ __forceinline__ float gload(const float* p) {
  return __hip_atomic_load(p, __ATOMIC_RELAXED, __HIP_MEMORY_SCOPE_AGENT);
}

__global__ __launch_bounds__(1024) void ctrl_fused(
    const float* __restrict__ enc_w,
    const float* __restrict__ wih,
    const float* __restrict__ whh,
    const float* __restrict__ b_ih,
    const float* __restrict__ b_hh,
    const float* __restrict__ w1,
    const float* __restrict__ w2,
    const float* __restrict__ vvec,
    unsigned char* __restrict__ ws,
    float* __restrict__ out) {

  const int b = blockIdx.x & 7;      // XCD swizzle: chain b -> XCD b (if RR)
  const int p = blockIdx.x >> 3;
  if (b >= NBLK) return;
  const int tid = threadIdx.x;

  int*   slots = (int*)(ws + OFF_BAR) + b * 16;
  int*   ready = (int*)(ws + OFF_READY);
  int*   done  = (int*)(ws + OFF_DONE);
  float* part  = (float*)(ws + OFF_PART);
  float* lpg   = (float*)(ws + OFF_LPG) + b * 64;
  float* hg    = (float*)(ws + OFF_HG);

  // chain-local barrier init by (b, p=0); others handshake on ready magic
  if (p == 0 && tid == 0) {
    for (int i = 0; i < PWG; ++i)
      __hip_atomic_store(&slots[i], 0, __ATOMIC_RELAXED,
                         __HIP_MEMORY_SCOPE_AGENT);
    __hip_atomic_store(&ready[b], READY_MAGIC, __ATOMIC_RELEASE,
                       __HIP_MEMORY_SCOPE_AGENT);
  }

  // 1024-row GEMV decomposition: 128 local rows x 8 k-slices of 32
  const int rl = tid >> 3, s = tid & 7;
  const int g = rl >> 5, el = rl & 31;
  const int row = g * 256 + p * 32 + el;
  const int k0 = s * 32;
  // 256-row GEMV decomposition: 32 local rows x 32 k-slices of 8
  const int rl2 = tid >> 5, s2 = tid & 31;
  const int row2 = p * 32 + rl2;
  const int k02 = s2 * 8;
  const int t4 = s2 >> 2;            // LDS rotation for conflict-free reads

  __shared__ __align__(16) float hL[256], encL[256];
  __shared__ __align__(16) float anchL[4][256];    // LDS-local anchors
  __shared__ __align__(16) float partL[1024];
  __shared__ __align__(16) float rowSumL[128];
  __shared__ float vS[32], biasS[128], w2hS[32];
  __shared__ float aw1S[7][32];
  __shared__ float logitPGL[48];
  __shared__ int   selL;

  if (tid < 256) encL[tid] = enc_w[tid];
  if (tid < 32)  vS[tid] = vvec[p * 32 + tid];
  if (tid < 128) {
    int gg = tid >> 5, ee = tid & 31, r = gg * 256 + p * 32 + ee;
    biasS[tid] = b_ih[r] + b_hh[r];
  }

  // register-resident weight slices (rotated chunk order -> conflict-free x)
  float4 wihr[8], whhr[8];
  #pragma unroll
  for (int c = 0; c < 8; ++c) {
    int cc = (c + s) & 7;
    wihr[c] = *(const float4*)(wih + row * 256 + k0 + cc * 4);
    whhr[c] = *(const float4*)(whh + row * 256 + k0 + cc * 4);
  }
  float w1r[8], w2r[8];
  #pragma unroll
  for (int j = 0; j < 8; ++j) {
    int jj = (j + t4) & 7;
    w1r[j] = w1[row2 * 256 + k02 + jj];
    w2r[j] = w2[row2 * 256 + k02 + jj];
  }

  if (tid == 0) {                    // ready handshake (overlapped w/ loads)
    while (__hip_atomic_load(&ready[b], __ATOMIC_ACQUIRE,
                             __HIP_MEMORY_SCOPE_AGENT) != READY_MAGIC)
      __builtin_amdgcn_s_sleep(1);
  }
  __syncthreads();

  auto dotIH = [&](const float* x) {
    float acc = 0.0f;
    #pragma unroll
    for (int c = 0; c < 8; ++c) {
      int cc = (c + s) & 7;
      float4 xv = *(const float4*)(x + k0 + cc * 4);
      float4 w = wihr[c];
      acc += w.x * xv.x + w.y * xv.y + w.z * xv.z + w.w * xv.w;
    }
    return acc;
  };
  auto dotHH = [&]() {
    float acc = 0.0f;
    #pragma unroll
    for (int c = 0; c < 8; ++c) {
      int cc = (c + s) & 7;
      float4 xv = *(const float4*)(hL + k0 + cc * 4);
      float4 w = whhr[c];
      acc += w.x * xv.x + w.y * xv.y + w.z * xv.z + w.w * xv.w;
    }
    return acc;
  };
  auto dotW1 = [&]() {
    float acc = 0.0f;
    #pragma unroll
    for (int j = 0; j < 8; ++j) acc += w1r[j] * hL[k02 + ((j + t4) & 7)];
    return acc;
  };
  auto dotW2 = [&]() {
    float acc = 0.0f;
    #pragma unroll
    for (int j = 0; j < 8; ++j) acc += w2r[j] * hL[k02 + ((j + t4) & 7)];
    return acc;
  };

  const float encih = dotIH(encL);   // wih @ enc, reused by all enc cells

  float cv = 0.0f;                            // c for element p*32+tid (tid<32)
  U2 bk = tf2x32(0u, 42u, 0u, (uint32_t)b);   // fold_in(key(42), b)
  int phase = 0, wpar = 0, step = 0;
  float lpAcc = 0.0f, entAcc = 0.0f;

  // flag-array barrier: parallel release-arrivals, parallel acquire-polls
  auto barrier8 = [&]() {
    __syncthreads();                 // drains all wg global stores (vmcnt 0)
    ++phase;
    if (tid == 0)
      __hip_atomic_store(&slots[p], phase, __ATOMIC_RELEASE,
                         __HIP_MEMORY_SCOPE_AGENT);
    if (tid < PWG) {
      while (__hip_atomic_load(&slots[tid], __ATOMIC_ACQUIRE,
                               __HIP_MEMORY_SCOPE_AGENT) < phase)
        __builtin_amdgcn_s_sleep(1);
    }
    __syncthreads();
  };

  // acc -> gates -> c,h update; exchange h; restage (and LDS-anchor copy).
  auto cellUpdate = [&](float acc, bool isAnchor, int aid, bool lastCell) {
    partL[tid] = acc;
    __syncthreads();
    if (tid < 128) {
      float ssum = 0.0f;
      #pragma unroll
      for (int j = 0; j < 8; ++j) ssum += partL[tid * 8 + j];
      rowSumL[tid] = ssum + biasS[tid];
    }
    __syncthreads();
    if (tid < 32) {
      float gi = rowSumL[tid],       gf = rowSumL[32 + tid];
      float gg2 = rowSumL[64 + tid], go = rowSumL[96 + tid];
      float c2 = sigf(gf) * cv + sigf(gi) * tanhf(gg2);
      float h2 = sigf(go) * tanhf(c2);
      cv = c2;
      int e = p * 32 + tid;
      if (!lastCell) gstore(&hg[wpar * (NBLK * 256) + b * 256 + e], h2);
      if (lastCell && b == NBLK - 1) { out[62 + e] = cv; out[318 + e] = h2; }
    }
    if (!lastCell) {
      barrier8();
      if (tid < 256) {
        float hv = gload(&hg[wpar * (NBLK * 256) + b * 256 + tid]);
        hL[tid] = hv;
        if (isAnchor) anchL[aid][tid] = hv;
      }
      wpar ^= 1;
      __syncthreads();
    }
  };

  auto doAw1 = [&](int aid) {        // local 32-slice of w1 @ h, stays in LDS
    float a1 = dotW1();
    a1 += __shfl_down(a1, 16, 32);
    a1 += __shfl_down(a1, 8, 32);
    a1 += __shfl_down(a1, 4, 32);
    a1 += __shfl_down(a1, 2, 32);
    a1 += __shfl_down(a1, 1, 32);
    if (s2 == 0) aw1S[aid][rl2] = a1;
    __syncthreads();
  };

  auto doSample = [&](int L) -> int {
    float a2 = dotW2();              // local 32-slice of w2 @ h
    a2 += __shfl_down(a2, 16, 32);
    a2 += __shfl_down(a2, 8, 32);
    a2 += __shfl_down(a2, 4, 32);
    a2 += __shfl_down(a2, 2, 32);
    a2 += __shfl_down(a2, 1, 32);
    if (s2 == 0) w2hS[rl2] = a2;
    __syncthreads();
    // logit partials over this wg's k-slice: wave i handles logit i
    int wv = tid >> 6, lane = tid & 63;
    if (wv < L && lane < 32) {
      float t = tanhf(aw1S[wv][lane] + w2hS[lane]) * vS[lane];
      t += __shfl_down(t, 16, 32);
      t += __shfl_down(t, 8, 32);
      t += __shfl_down(t, 4, 32);
      t += __shfl_down(t, 2, 32);
      t += __shfl_down(t, 1, 32);
      if (lane == 0) gstore(&lpg[wv * 8 + p], t);
    }
    barrier8();
    if (tid < 8 * L) logitPGL[tid] = gload(&lpg[tid]);
    __syncthreads();
    if (tid < 64) {                  // wave 0: lane-parallel selection
      float lg = 0.0f, sgum = -1e30f;
      if (tid < L) {
        float ls = 0.0f;
        for (int j = 0; j < 8; ++j) ls += logitPGL[tid * 8 + j];
        lg = 1.1f * tanhf(ls * 0.2f);
        U2 sk = tf2x32(bk.x, bk.y, 0u, (uint32_t)step);
        U2 r2 = tf2x32(sk.x, sk.y, 0u, (uint32_t)tid);
        uint32_t bits = r2.x ^ r2.y;
        float u = __uint_as_float((bits >> 9) | 0x3f800000u) - 1.0f;
        u = fmaxf(TINYF, u + TINYF);
        sgum = lg - logf(-logf(u));
      }
      int bi = 0;
      float best = __shfl(sgum, 0, 64);
      for (int j = 1; j < L; ++j) {
        float sj = __shfl(sgum, j, 64);
        if (sj > best) { best = sj; bi = j; }  // first-max = jnp.argmax
      }
      float mx = __shfl(lg, 0, 64);
      for (int j = 1; j < L; ++j) mx = fmaxf(mx, __shfl(lg, j, 64));
      float se = 0.0f;
      for (int j = 0; j < L; ++j) se += expf(__shfl(lg, j, 64) - mx);
      float lse = logf(se);
      float lgbi = __shfl(lg, bi, 64);
      float es = 0.0f;
      for (int j = 0; j < L; ++j) {
        float l = __shfl(lg, j, 64) - mx - lse;
        es += l * expf(l);
      }
      if (tid == 0) {
        lpAcc += -(lgbi - mx - lse);
        entAcc += -es;
        selL = bi;
        if (p == 0) out[b * 10 + step] = (float)bi;
      }
    }
    __syncthreads();
    step++;
    return selL;
  };

  // ---- chain ----
  cellUpdate(encih, false, 0, false);          // zero-state cell (run once)
  doAw1(0);
  if (tid < 32) aw1S[1][tid] = aw1S[0][tid];
  __syncthreads();

  for (int L = 2; L <= 6; ++L) {
    cellUpdate(encih + dotHH(), false, 0, false);
    int s1v = doSample(L);
    {
      float acc = (s1v >= 2) ? dotIH(&anchL[s1v - 2][0]) : 0.0f;
      cellUpdate(acc + dotHH(), false, 0, false);
    }
    int s2v = doSample(L);
    {
      float acc = (s2v >= 2) ? dotIH(&anchL[s2v - 2][0]) : 0.0f;
      cellUpdate(acc + dotHH(), L < 6, L - 2, L == 6);
    }
    if (L < 6) doAw1(L);
  }

  // final lp/ent reduction: done-magic flags, summed by block (5, p=0)
  if (p == 0 && tid == 0) {
    gstore(&part[2 * b], lpAcc);
    gstore(&part[2 * b + 1], entAcc);
    __hip_atomic_store(&done[b], DONE_MAGIC, __ATOMIC_RELEASE,
                       __HIP_MEMORY_SCOPE_AGENT);
    if (b == NBLK - 1) {
      float lp = 0.0f, en = 0.0f;
      for (int j = 0; j < NBLK; ++j) {
        while (__hip_atomic_load(&done[j], __ATOMIC_ACQUIRE,
                                 __HIP_MEMORY_SCOPE_AGENT) != DONE_MAGIC)
          __builtin_amdgcn_s_sleep(1);
        lp += gload(&part[2 * j]);
        en += gload(&part[2 * j + 1]);
      }
      out[60] = lp;
      out[61] = en;
    }
  }
}

extern "C" void kernel_launch(void* const* d_in, const int* in_sizes, int n_in,
                              void* d_out, int out_size, void* d_ws, size_t ws_size,
                              hipStream_t stream) {
  const float* enc = (const float*)d_in[0];
  const float* wih = (const float*)d_in[1];
  const float* whh = (const float*)d_in[2];
  const float* bih = (const float*)d_in[3];
  const float* bhh = (const float*)d_in[4];
  const float* w1  = (const float*)d_in[5];
  const float* w2  = (const float*)d_in[6];
  const float* v   = (const float*)d_in[7];
  unsigned char* ws = (unsigned char*)d_ws;
  float* out = (float*)d_out;

  // single fused launch; 64 blocks so chain b's 8 wgs share XCD b (RR dispatch)
  ctrl_fused<<<dim3(64), dim3(1024), 0, stream>>>(
      enc, wih, whh, bih, bhh, w1, w2, v, ws, out);
}

// Round 7
// 170.065 us; speedup vs baseline: 4.4395x; 1.1182x over previous
//
#include <hip/hip_runtime.h>
#include <stdint.h>

// ENAS LSTM controller. R7 = R6 with FENCE-FREE synchronization.
// R6 evidence: FETCH_SIZE grew 4.7->10.2MB and steps cost ~4.8us; cause =
// acquire/release at agent scope lowering to buffer_wbl2/buffer_inv sc1 (L2
// writeback/invalidate) -- the acquire sat in the poll loop, invalidating L2
// every iteration. All cross-wg data here moves via RELAXED agent atomics
// (LLC-resolved), and __syncthreads() drains vmcnt before every flag store,
// so release/acquire fences are unnecessary: flags+data use relaxed ordering
// only. Single-thread store->store ordering (slots->ready, part->done) uses
// explicit s_waitcnt(0). Math identical to bit-exact R6 (absmax 0).

#define NBLK  6
#define PWG   8
#define TINYF 1.17549435e-38f

#define OFF_BAR   0u      // int[8][16]: per-chain 8 slots (64B-spaced chains)
#define OFF_READY 512u    // int[8] ready magic
#define OFF_DONE  544u    // int[8] done magic
#define OFF_PART  576u    // float[16] lp/ent per chain
#define OFF_LPG   640u    // float[6][64] logit partials
#define OFF_HG    2176u   // float[2][6][256] double-buffered h
#define WS_NEED   14464u

#define READY_MAGIC 0x52454459
#define DONE_MAGIC  0x444f4e45

struct U2 { uint32_t x, y; };

// Threefry-2x32, 20 rounds (Random123 / JAX). Key (k0,k1), counter (c0,c1).
__device__ __forceinline__ U2 tf2x32(uint32_t k0, uint32_t k1,
                                     uint32_t c0, uint32_t c1) {
  uint32_t ks2 = k0 ^ k1 ^ 0x1BD11BDAu;
  uint32_t x0 = c0 + k0, x1 = c1 + k1;
#define TFR(r) { x0 += x1; x1 = (x1 << (r)) | (x1 >> (32 - (r))); x1 ^= x0; }
  TFR(13) TFR(15) TFR(26) TFR(6)   x0 += k1;  x1 += ks2 + 1u;
  TFR(17) TFR(29) TFR(16) TFR(24)  x0 += ks2; x1 += k0 + 2u;
  TFR(13) TFR(15) TFR(26) TFR(6)   x0 += k0;  x1 += k1 + 3u;
  TFR(17) TFR(29) TFR(16) TFR(24)  x0 += k1;  x1 += ks2 + 4u;
  TFR(13) TFR(15) TFR(26) TFR(6)   x0 += ks2; x1 += k0 + 5u;
#undef TFR
  U2 r; r.x = x0; r.y = x1; return r;
}

__device__ __forceinline__ float sigf(float x) {
  return 1.0f / (1.0f + expf(-x));
}
// ALL relaxed, agent scope (sc0|sc1: bypass L1/L2, resolve at LLC). No fences.
__device__ __forceinline__ void gstore(float* p, float v) {
  __hip_atomic_store(p, v, __ATOMIC_RELAXED, __HIP_MEMORY_SCOPE_AGENT);
}
__device__ __forceinline__ float gload(const float* p) {
  return __hip_atomic_load(p, __ATOMIC_RELAXED, __HIP_MEMORY_SCOPE_AGENT);
}
__device__ __forceinline__ void istore(int* p, int v) {
  __hip_atomic_store(p, v, __ATOMIC_RELAXED, __HIP_MEMORY_SCOPE_AGENT);
}
__device__ __forceinline__ int iload(const int* p) {
  return __hip_atomic_load(p, __ATOMIC_RELAXED, __HIP_MEMORY_SCOPE_AGENT);
}

__global__ __launch_bounds__(1024) void ctrl_fused(
    const float* __restrict__ enc_w,
    const float* __restrict__ wih,
    const float* __restrict__ whh,
    const float* __restrict__ b_ih,
    const float* __restrict__ b_hh,
    const float* __restrict__ w1,
    const float* __restrict__ w2,
    const float* __restrict__ vvec,
    unsigned char* __restrict__ ws,
    float* __restrict__ out) {

  const int b = blockIdx.x & 7;      // XCD swizzle: chain b -> XCD b (if RR)
  const int p = blockIdx.x >> 3;
  if (b >= NBLK) return;
  const int tid = threadIdx.x;

  int*   slots = (int*)(ws + OFF_BAR) + b * 16;
  int*   ready = (int*)(ws + OFF_READY);
  int*   done  = (int*)(ws + OFF_DONE);
  float* part  = (float*)(ws + OFF_PART);
  float* lpg   = (float*)(ws + OFF_LPG) + b * 64;
  float* hg    = (float*)(ws + OFF_HG);

  // chain-local barrier init by (b, p=0); others handshake on ready magic.
  // slots stores drained (s_waitcnt 0) BEFORE ready store: relaxed-only safe.
  if (p == 0 && tid == 0) {
    for (int i = 0; i < PWG; ++i) istore(&slots[i], 0);
    __builtin_amdgcn_s_waitcnt(0);
    istore(&ready[b], READY_MAGIC);
  }

  // 1024-row GEMV decomposition: 128 local rows x 8 k-slices of 32
  const int rl = tid >> 3, s = tid & 7;
  const int g = rl >> 5, el = rl & 31;
  const int row = g * 256 + p * 32 + el;
  const int k0 = s * 32;
  // 256-row GEMV decomposition: 32 local rows x 32 k-slices of 8
  const int rl2 = tid >> 5, s2 = tid & 31;
  const int row2 = p * 32 + rl2;
  const int k02 = s2 * 8;
  const int t4 = s2 >> 2;            // LDS rotation for conflict-free reads

  __shared__ __align__(16) float hL[256], encL[256];
  __shared__ __align__(16) float anchL[4][256];    // LDS-local anchors
  __shared__ __align__(16) float partL[1024];
  __shared__ __align__(16) float rowSumL[128];
  __shared__ float vS[32], biasS[128], w2hS[32];
  __shared__ float aw1S[7][32];
  __shared__ float logitPGL[48];
  __shared__ int   selL;

  if (tid < 256) encL[tid] = enc_w[tid];
  if (tid < 32)  vS[tid] = vvec[p * 32 + tid];
  if (tid < 128) {
    int gg = tid >> 5, ee = tid & 31, r = gg * 256 + p * 32 + ee;
    biasS[tid] = b_ih[r] + b_hh[r];
  }

  // register-resident weight slices (rotated chunk order -> conflict-free x)
  float4 wihr[8], whhr[8];
  #pragma unroll
  for (int c = 0; c < 8; ++c) {
    int cc = (c + s) & 7;
    wihr[c] = *(const float4*)(wih + row * 256 + k0 + cc * 4);
    whhr[c] = *(const float4*)(whh + row * 256 + k0 + cc * 4);
  }
  float w1r[8], w2r[8];
  #pragma unroll
  for (int j = 0; j < 8; ++j) {
    int jj = (j + t4) & 7;
    w1r[j] = w1[row2 * 256 + k02 + jj];
    w2r[j] = w2[row2 * 256 + k02 + jj];
  }

  if (tid == 0) {                    // ready handshake (overlapped w/ loads)
    while (iload(&ready[b]) != READY_MAGIC) __builtin_amdgcn_s_sleep(1);
  }
  __syncthreads();

  auto dotIH = [&](const float* x) {
    float acc = 0.0f;
    #pragma unroll
    for (int c = 0; c < 8; ++c) {
      int cc = (c + s) & 7;
      float4 xv = *(const float4*)(x + k0 + cc * 4);
      float4 w = wihr[c];
      acc += w.x * xv.x + w.y * xv.y + w.z * xv.z + w.w * xv.w;
    }
    return acc;
  };
  auto dotHH = [&]() {
    float acc = 0.0f;
    #pragma unroll
    for (int c = 0; c < 8; ++c) {
      int cc = (c + s) & 7;
      float4 xv = *(const float4*)(hL + k0 + cc * 4);
      float4 w = whhr[c];
      acc += w.x * xv.x + w.y * xv.y + w.z * xv.z + w.w * xv.w;
    }
    return acc;
  };
  auto dotW1 = [&]() {
    float acc = 0.0f;
    #pragma unroll
    for (int j = 0; j < 8; ++j) acc += w1r[j] * hL[k02 + ((j + t4) & 7)];
    return acc;
  };
  auto dotW2 = [&]() {
    float acc = 0.0f;
    #pragma unroll
    for (int j = 0; j < 8; ++j) acc += w2r[j] * hL[k02 + ((j + t4) & 7)];
    return acc;
  };

  const float encih = dotIH(encL);   // wih @ enc, reused by all enc cells

  float cv = 0.0f;                            // c for element p*32+tid (tid<32)
  U2 bk = tf2x32(0u, 42u, 0u, (uint32_t)b);   // fold_in(key(42), b)
  int phase = 0, wpar = 0, step = 0;
  float lpAcc = 0.0f, entAcc = 0.0f;

  // fence-free flag barrier: __syncthreads drains vmcnt(0) (data at LLC)
  // before the relaxed flag store; pollers' data loads issue after the flag
  // load returns the new phase -> ordered without acquire/release fences.
  auto barrier8 = [&]() {
    __syncthreads();
    ++phase;
    if (tid == 0) istore(&slots[p], phase);
    if (tid < PWG) {
      while (iload(&slots[tid]) < phase) __builtin_amdgcn_s_sleep(1);
    }
    __syncthreads();
  };

  // acc -> gates -> c,h update; exchange h; restage (and LDS-anchor copy).
  auto cellUpdate = [&](float acc, bool isAnchor, int aid, bool lastCell) {
    partL[tid] = acc;
    __syncthreads();
    if (tid < 128) {
      float ssum = 0.0f;
      #pragma unroll
      for (int j = 0; j < 8; ++j) ssum += partL[tid * 8 + j];
      rowSumL[tid] = ssum + biasS[tid];
    }
    __syncthreads();
    if (tid < 32) {
      float gi = rowSumL[tid],       gf = rowSumL[32 + tid];
      float gg2 = rowSumL[64 + tid], go = rowSumL[96 + tid];
      float c2 = sigf(gf) * cv + sigf(gi) * tanhf(gg2);
      float h2 = sigf(go) * tanhf(c2);
      cv = c2;
      int e = p * 32 + tid;
      if (!lastCell) gstore(&hg[wpar * (NBLK * 256) + b * 256 + e], h2);
      if (lastCell && b == NBLK - 1) { out[62 + e] = cv; out[318 + e] = h2; }
    }
    if (!lastCell) {
      barrier8();
      if (tid < 256) {
        float hv = gload(&hg[wpar * (NBLK * 256) + b * 256 + tid]);
        hL[tid] = hv;
        if (isAnchor) anchL[aid][tid] = hv;
      }
      wpar ^= 1;
      __syncthreads();
    }
  };

  auto doAw1 = [&](int aid) {        // local 32-slice of w1 @ h, stays in LDS
    float a1 = dotW1();
    a1 += __shfl_down(a1, 16, 32);
    a1 += __shfl_down(a1, 8, 32);
    a1 += __shfl_down(a1, 4, 32);
    a1 += __shfl_down(a1, 2, 32);
    a1 += __shfl_down(a1, 1, 32);
    if (s2 == 0) aw1S[aid][rl2] = a1;
    __syncthreads();
  };

  auto doSample = [&](int L) -> int {
    float a2 = dotW2();              // local 32-slice of w2 @ h
    a2 += __shfl_down(a2, 16, 32);
    a2 += __shfl_down(a2, 8, 32);
    a2 += __shfl_down(a2, 4, 32);
    a2 += __shfl_down(a2, 2, 32);
    a2 += __shfl_down(a2, 1, 32);
    if (s2 == 0) w2hS[rl2] = a2;
    __syncthreads();
    // logit partials over this wg's k-slice: wave i handles logit i
    int wv = tid >> 6, lane = tid & 63;
    if (wv < L && lane < 32) {
      float t = tanhf(aw1S[wv][lane] + w2hS[lane]) * vS[lane];
      t += __shfl_down(t, 16, 32);
      t += __shfl_down(t, 8, 32);
      t += __shfl_down(t, 4, 32);
      t += __shfl_down(t, 2, 32);
      t += __shfl_down(t, 1, 32);
      if (lane == 0) gstore(&lpg[wv * 8 + p], t);
    }
    barrier8();
    if (tid < 8 * L) logitPGL[tid] = gload(&lpg[tid]);
    __syncthreads();
    if (tid < 64) {                  // wave 0: lane-parallel selection
      float lg = 0.0f, sgum = -1e30f;
      if (tid < L) {
        float ls = 0.0f;
        for (int j = 0; j < 8; ++j) ls += logitPGL[tid * 8 + j];
        lg = 1.1f * tanhf(ls * 0.2f);
        U2 sk = tf2x32(bk.x, bk.y, 0u, (uint32_t)step);
        U2 r2 = tf2x32(sk.x, sk.y, 0u, (uint32_t)tid);
        uint32_t bits = r2.x ^ r2.y;
        float u = __uint_as_float((bits >> 9) | 0x3f800000u) - 1.0f;
        u = fmaxf(TINYF, u + TINYF);
        sgum = lg - logf(-logf(u));
      }
      int bi = 0;
      float best = __shfl(sgum, 0, 64);
      for (int j = 1; j < L; ++j) {
        float sj = __shfl(sgum, j, 64);
        if (sj > best) { best = sj; bi = j; }  // first-max = jnp.argmax
      }
      float mx = __shfl(lg, 0, 64);
      for (int j = 1; j < L; ++j) mx = fmaxf(mx, __shfl(lg, j, 64));
      float se = 0.0f;
      for (int j = 0; j < L; ++j) se += expf(__shfl(lg, j, 64) - mx);
      float lse = logf(se);
      float lgbi = __shfl(lg, bi, 64);
      float es = 0.0f;
      for (int j = 0; j < L; ++j) {
        float l = __shfl(lg, j, 64) - mx - lse;
        es += l * expf(l);
      }
      if (tid == 0) {
        lpAcc += -(lgbi - mx - lse);
        entAcc += -es;
        selL = bi;
        if (p == 0) out[b * 10 + step] = (float)bi;
      }
    }
    __syncthreads();
    step++;
    return selL;
  };

  // ---- chain ----
  cellUpdate(encih, false, 0, false);          // zero-state cell (run once)
  doAw1(0);
  if (tid < 32) aw1S[1][tid] = aw1S[0][tid];
  __syncthreads();

  for (int L = 2; L <= 6; ++L) {
    cellUpdate(encih + dotHH(), false, 0, false);
    int s1v = doSample(L);
    {
      float acc = (s1v >= 2) ? dotIH(&anchL[s1v - 2][0]) : 0.0f;
      cellUpdate(acc + dotHH(), false, 0, false);
    }
    int s2v = doSample(L);
    {
      float acc = (s2v >= 2) ? dotIH(&anchL[s2v - 2][0]) : 0.0f;
      cellUpdate(acc + dotHH(), L < 6, L - 2, L == 6);
    }
    if (L < 6) doAw1(L);
  }

  // final lp/ent reduction: done flags, summed by chain 5's p=0 wg.
  // part stores drained (s_waitcnt 0) before done store: relaxed-only safe.
  if (p == 0 && tid == 0) {
    gstore(&part[2 * b], lpAcc);
    gstore(&part[2 * b + 1], entAcc);
    __builtin_amdgcn_s_waitcnt(0);
    istore(&done[b], DONE_MAGIC);
    if (b == NBLK - 1) {
      float lp = 0.0f, en = 0.0f;
      for (int j = 0; j < NBLK; ++j) {
        while (iload(&done[j]) != DONE_MAGIC) __builtin_amdgcn_s_sleep(1);
        lp += gload(&part[2 * j]);
        en += gload(&part[2 * j + 1]);
      }
      out[60] = lp;
      out[61] = en;
    }
  }
}

extern "C" void kernel_launch(void* const* d_in, const int* in_sizes, int n_in,
                              void* d_out, int out_size, void* d_ws, size_t ws_size,
                              hipStream_t stream) {
  const float* enc = (const float*)d_in[0];
  const float* wih = (const float*)d_in[1];
  const float* whh = (const float*)d_in[2];
  const float* bih = (const float*)d_in[3];
  const float* bhh = (const float*)d_in[4];
  const float* w1  = (const float*)d_in[5];
  const float* w2  = (const float*)d_in[6];
  const float* v   = (const float*)d_in[7];
  unsigned char* ws = (unsigned char*)d_ws;
  float* out = (float*)d_out;

  // single fused launch; 64 blocks so chain b's 8 wgs share XCD b (RR dispatch)
  ctrl_fused<<<dim3(64), dim3(1024), 0, stream>>>(
      enc, wih, whh, bih, bhh, w1, w2, v, ws, out);
}

// Round 8
// 155.665 us; speedup vs baseline: 4.8502x; 1.0925x over previous
//
#include <hip/hip_runtime.h>
#include <stdint.h>

// ENAS LSTM controller. R8: fuse the sample exchange into the cell exchange.
// Each of 6 chains runs on 8 wgs (grid 64, b=blockIdx&7 XCD swizzle).
// Per cell exchange, wg p publishes (a) its 32 h elements as packed
// (phase,float) 8B words -- readers poll the DATA, no separate flag hop --
// and (b) its column-slice partial of w2@h (or w1@h at anchor cells) via
// DETERMINISTIC fixed-point int32 atomicAdd (2^26 scale; integer adds are
// associative -> bit-reproducible; |sum| <= ~10 -> no overflow). Every wg
// then holds full w2h/aw1 and samples LOCALLY (identical result in all wgs):
// 26 exchanges -> 15. Accumulators triple-buffered, h double-buffered; reuse
// safety follows from phase ordering (posting k implies observed all k-1,
// implies all reads of k-2 done). ws usage 43,328 B (<= 44,976 proven in R5).
// PRNG / gates / selection math identical to bit-exact R7.

#define NBLK  6
#define PWG   8
#define TINYF 1.17549435e-38f
#define FXS   67108864.0f          // 2^26 fixed-point scale
#define READY_MAGIC 0x52454459
#define DONE_MAGIC  0x444f4e45

// ws layout (bytes), total 43328
#define OFF_READY 0u               // int[6][8]
#define OFF_DONE  192u             // int[8]
#define OFF_PART  224u             // float[12]
#define OFF_HP    320u             // u64 hpack[2][6][256]  (24576 B)
#define OFF_ACC   24896u           // int  acc[3][6][256]   (18432 B)

typedef unsigned long long u64;
struct U2 { uint32_t x, y; };

// Threefry-2x32, 20 rounds (Random123 / JAX). Key (k0,k1), counter (c0,c1).
__device__ __forceinline__ U2 tf2x32(uint32_t k0, uint32_t k1,
                                     uint32_t c0, uint32_t c1) {
  uint32_t ks2 = k0 ^ k1 ^ 0x1BD11BDAu;
  uint32_t x0 = c0 + k0, x1 = c1 + k1;
#define TFR(r) { x0 += x1; x1 = (x1 << (r)) | (x1 >> (32 - (r))); x1 ^= x0; }
  TFR(13) TFR(15) TFR(26) TFR(6)   x0 += k1;  x1 += ks2 + 1u;
  TFR(17) TFR(29) TFR(16) TFR(24)  x0 += ks2; x1 += k0 + 2u;
  TFR(13) TFR(15) TFR(26) TFR(6)   x0 += k0;  x1 += k1 + 3u;
  TFR(17) TFR(29) TFR(16) TFR(24)  x0 += k1;  x1 += ks2 + 4u;
  TFR(13) TFR(15) TFR(26) TFR(6)   x0 += ks2; x1 += k0 + 5u;
#undef TFR
  U2 r; r.x = x0; r.y = x1; return r;
}

__device__ __forceinline__ float sigf(float x) {
  return 1.0f / (1.0f + expf(-x));
}
// relaxed agent-scope (LLC-resolved) accessors; ordering via __syncthreads
// vmcnt drain + data-embedded phase tags (see R7 notes).
__device__ __forceinline__ void istore(int* p, int v) {
  __hip_atomic_store(p, v, __ATOMIC_RELAXED, __HIP_MEMORY_SCOPE_AGENT);
}
__device__ __forceinline__ int iload(const int* p) {
  return __hip_atomic_load(p, __ATOMIC_RELAXED, __HIP_MEMORY_SCOPE_AGENT);
}
__device__ __forceinline__ void hstore(u64* p, u64 v) {
  __hip_atomic_store(p, v, __ATOMIC_RELAXED, __HIP_MEMORY_SCOPE_AGENT);
}
__device__ __forceinline__ u64 hload(const u64* p) {
  return __hip_atomic_load(p, __ATOMIC_RELAXED, __HIP_MEMORY_SCOPE_AGENT);
}
__device__ __forceinline__ void fstore(float* p, float v) {
  __hip_atomic_store(p, v, __ATOMIC_RELAXED, __HIP_MEMORY_SCOPE_AGENT);
}
__device__ __forceinline__ float fload(const float* p) {
  return __hip_atomic_load(p, __ATOMIC_RELAXED, __HIP_MEMORY_SCOPE_AGENT);
}

__global__ __launch_bounds__(1024) void ctrl_fused(
    const float* __restrict__ enc_w,
    const float* __restrict__ wih,
    const float* __restrict__ whh,
    const float* __restrict__ b_ih,
    const float* __restrict__ b_hh,
    const float* __restrict__ w1,
    const float* __restrict__ w2,
    const float* __restrict__ vvec,
    unsigned char* __restrict__ ws,
    float* __restrict__ out) {

  const int b = blockIdx.x & 7;      // XCD swizzle: chain b -> XCD b (if RR)
  const int p = blockIdx.x >> 3;
  if (b >= NBLK) return;
  const int tid = threadIdx.x;

  int*   ready = (int*)(ws + OFF_READY);
  int*   done  = (int*)(ws + OFF_DONE);
  float* part  = (float*)(ws + OFF_PART);
  u64*   hp    = (u64*)(ws + OFF_HP);      // [2][6][256]
  int*   acc   = (int*)(ws + OFF_ACC);     // [3][6][256]

  // 1024-row gate GEMV: 128 local rows x 8 k-slices of 32
  const int rl = tid >> 3, s = tid & 7;
  const int g = rl >> 5, el = rl & 31;
  const int row = g * 256 + p * 32 + el;
  const int k0 = s * 32;
  // y-slice (column-block of w1/w2): row rr, 8 cols of own 32-block
  const int rr = tid & 255, ks = tid >> 2 >> 6;  // ks = tid>>8 in [0,4)

  __shared__ __align__(16) float hL[256], encL[256], vL[256];
  __shared__ __align__(16) float anchL[4][256];
  __shared__ __align__(16) float partL[1024];
  __shared__ __align__(16) float w2hS[256], aw1S[6][256];
  __shared__ float rowSumL[128], biasS[128], h2S[32];
  __shared__ float logitL[8];
  __shared__ int   selL;

  if (tid < 256) { encL[tid] = enc_w[tid]; vL[tid] = vvec[tid]; }
  if (tid < 128) {
    int gg = tid >> 5, ee = tid & 31, r = gg * 256 + p * 32 + ee;
    biasS[tid] = b_ih[r] + b_hh[r];
  }

  // register-resident weights: gate rows (rotated chunks, conflict-free LDS)
  float4 wihr[8], whhr[8];
  #pragma unroll
  for (int c = 0; c < 8; ++c) {
    int cc = (c + s) & 7;
    wihr[c] = *(const float4*)(wih + row * 256 + k0 + cc * 4);
    whhr[c] = *(const float4*)(whh + row * 256 + k0 + cc * 4);
  }
  // column-slices of w1/w2 for y partials: cols p*32 + ks*8 + j
  float w1c[8], w2c[8];
  #pragma unroll
  for (int j = 0; j < 8; ++j) {
    w1c[j] = w1[rr * 256 + p * 32 + ks * 8 + j];
    w2c[j] = w2[rr * 256 + p * 32 + ks * 8 + j];
  }

  // init: zero own slice of acc buffer 1 (first exchange), then ready gate
  if (tid < 32) istore(&acc[1 * (NBLK * 256) + b * 256 + p * 32 + tid], 0);
  __syncthreads();                   // drains zero stores (vmcnt 0)
  if (tid == 0) istore(&ready[b * 8 + p], READY_MAGIC);
  if (tid < 8) {
    while (iload(&ready[b * 8 + tid]) != READY_MAGIC)
      __builtin_amdgcn_s_sleep(1);
  }
  __syncthreads();

  auto dotIH = [&](const float* x) {
    float a = 0.0f;
    #pragma unroll
    for (int c = 0; c < 8; ++c) {
      int cc = (c + s) & 7;
      float4 xv = *(const float4*)(x + k0 + cc * 4);
      float4 w = wihr[c];
      a += w.x * xv.x + w.y * xv.y + w.z * xv.z + w.w * xv.w;
    }
    return a;
  };
  auto dotHH = [&]() {
    float a = 0.0f;
    #pragma unroll
    for (int c = 0; c < 8; ++c) {
      int cc = (c + s) & 7;
      float4 xv = *(const float4*)(hL + k0 + cc * 4);
      float4 w = whhr[c];
      a += w.x * xv.x + w.y * xv.y + w.z * xv.z + w.w * xv.w;
    }
    return a;
  };

  const float encih = dotIH(encL);   // wih @ enc, reused by all enc cells

  float cv = 0.0f;                            // c for element p*32+tid (tid<32)
  U2 bk = tf2x32(0u, 42u, 0u, (uint32_t)b);   // fold_in(key(42), b)
  int k = 1, step = 0;
  float lpAcc = 0.0f, entAcc = 0.0f;

  // One cell + fused exchange. mode: 0 = publish w2 partials -> w2hS,
  // 1 = publish w1 partials -> aw1S[aid] (+ anchor copy to anchL[cid]),
  // 2 = last cell (no exchange).
  auto cell = [&](float gacc, int mode, int aid, int cid) {
    partL[tid] = gacc;
    __syncthreads();
    if (tid < 128) {
      float ssum = 0.0f;
      #pragma unroll
      for (int j = 0; j < 8; ++j) ssum += partL[tid * 8 + j];
      rowSumL[tid] = ssum + biasS[tid];
    }
    __syncthreads();
    if (tid < 32) {
      float gi = rowSumL[tid],       gf = rowSumL[32 + tid];
      float gg2 = rowSumL[64 + tid], go = rowSumL[96 + tid];
      float c2 = sigf(gf) * cv + sigf(gi) * tanhf(gg2);
      float h2 = sigf(go) * tanhf(c2);
      cv = c2;
      h2S[tid] = h2;
      if (mode == 2 && b == NBLK - 1) {
        out[62 + p * 32 + tid] = cv;
        out[318 + p * 32 + tid] = h2;
      }
    }
    __syncthreads();                 // h2S visible to all
    if (mode == 2) return;

    // y partial (column-slice) -> fixed-point atomic accumulate
    {
      const float* wc = (mode == 1) ? w1c : w2c;
      float yp = 0.0f;
      #pragma unroll
      for (int j = 0; j < 8; ++j) yp += wc[j] * h2S[ks * 8 + j];
      atomicAdd(&acc[(k % 3) * (NBLK * 256) + b * 256 + rr],
                __float2int_rn(yp * FXS));
      // pre-zero buffer (k+1)%3 == (k-2)%3 (all reads of k-2 provably done)
      if (tid < 32)
        istore(&acc[((k + 1) % 3) * (NBLK * 256) + b * 256 + p * 32 + tid], 0);
    }
    __syncthreads();                 // vmcnt(0): adds+zeroes at LLC
    // publish packed (phase, h) -- the tag IS the barrier
    if (tid < 32) {
      u64 pk = ((u64)(uint32_t)k << 32) | (u64)__float_as_uint(h2S[tid]);
      hstore(&hp[(k & 1) * (NBLK * 256) + b * 256 + p * 32 + tid], pk);
    }
    // poll data tags (one LLC object per element)
    if (tid < 256) {
      u64 v;
      const u64* src = &hp[(k & 1) * (NBLK * 256) + b * 256 + tid];
      while ((int)(hload(src) >> 32) != k) __builtin_amdgcn_s_sleep(1);
      v = hload(src);
      float hv = __uint_as_float((uint32_t)v);
      hL[tid] = hv;
      if (mode == 1 && cid >= 0) anchL[cid][tid] = hv;
    }
    __syncthreads();                 // all tags observed -> acc loads valid
    if (tid < 256) {
      int iv = iload(&acc[(k % 3) * (NBLK * 256) + b * 256 + tid]);
      float f = (float)((double)iv * (1.0 / 67108864.0));
      if (mode == 1) aw1S[aid][tid] = f; else w2hS[tid] = f;
    }
    __syncthreads();
    ++k;
  };

  // local sample: identical in every wg (deterministic fixed-point inputs)
  auto sample = [&](int L) -> int {
    int wv = tid >> 6, lane = tid & 63;
    if (wv < L) {
      float a = 0.0f;
      #pragma unroll
      for (int j = 0; j < 4; ++j) {
        int kk = lane * 4 + j;
        a += tanhf(aw1S[wv][kk] + w2hS[kk]) * vL[kk];
      }
      a += __shfl_down(a, 32);
      a += __shfl_down(a, 16);
      a += __shfl_down(a, 8);
      a += __shfl_down(a, 4);
      a += __shfl_down(a, 2);
      a += __shfl_down(a, 1);
      if (lane == 0) logitL[wv] = a;
    }
    __syncthreads();
    if (tid < 64) {                  // wave 0: lane-parallel selection
      float lg = 0.0f, sgum = -1e30f;
      if (tid < L) {
        lg = 1.1f * tanhf(logitL[tid] * 0.2f);
        U2 sk = tf2x32(bk.x, bk.y, 0u, (uint32_t)step);
        U2 r2 = tf2x32(sk.x, sk.y, 0u, (uint32_t)tid);
        uint32_t bits = r2.x ^ r2.y;
        float u = __uint_as_float((bits >> 9) | 0x3f800000u) - 1.0f;
        u = fmaxf(TINYF, u + TINYF); // jax uniform(minval=tiny, maxval=1)
        sgum = lg - logf(-logf(u));
      }
      int bi = 0;
      float best = __shfl(sgum, 0, 64);
      for (int j = 1; j < L; ++j) {
        float sj = __shfl(sgum, j, 64);
        if (sj > best) { best = sj; bi = j; }  // first-max = jnp.argmax
      }
      float mx = __shfl(lg, 0, 64);
      for (int j = 1; j < L; ++j) mx = fmaxf(mx, __shfl(lg, j, 64));
      float se = 0.0f;
      for (int j = 0; j < L; ++j) se += expf(__shfl(lg, j, 64) - mx);
      float lse = logf(se);
      float lgbi = __shfl(lg, bi, 64);
      float es = 0.0f;
      for (int j = 0; j < L; ++j) {
        float l = __shfl(lg, j, 64) - mx - lse;
        es += l * expf(l);
      }
      if (tid == 0) {
        lpAcc += -(lgbi - mx - lse);
        entAcc += -es;
        selL = bi;
        if (p == 0) out[b * 10 + step] = (float)bi;
      }
    }
    __syncthreads();
    step++;
    return selL;
  };

  // ---- chain ----
  cell(encih, 1, 0, -1);             // zero-state cell; publishes aw1[0]
  if (tid < 256) aw1S[1][tid] = aw1S[0][tid];
  __syncthreads();

  for (int L = 2; L <= 6; ++L) {
    cell(encih + dotHH(), 0, 0, -1);                 // -> w2hS
    int s1v = sample(L);
    {
      float a = (s1v >= 2) ? dotIH(&anchL[s1v - 2][0]) : 0.0f;
      cell(a + dotHH(), 0, 0, -1);                   // -> w2hS
    }
    int s2v = sample(L);
    {
      float a = (s2v >= 2) ? dotIH(&anchL[s2v - 2][0]) : 0.0f;
      if (L < 6) cell(a + dotHH(), 1, L, L - 2);     // -> aw1S[L] + anchor
      else       cell(a + dotHH(), 2, 0, -1);        // last cell, no exchange
    }
  }

  // final lp/ent reduction: done flags, summed by chain 5's p=0 wg
  if (p == 0 && tid == 0) {
    fstore(&part[2 * b], lpAcc);
    fstore(&part[2 * b + 1], entAcc);
    __builtin_amdgcn_s_waitcnt(0);
    istore(&done[b], DONE_MAGIC);
    if (b == NBLK - 1) {
      float lp = 0.0f, en = 0.0f;
      for (int j = 0; j < NBLK; ++j) {
        while (iload(&done[j]) != DONE_MAGIC) __builtin_amdgcn_s_sleep(1);
        lp += fload(&part[2 * j]);
        en += fload(&part[2 * j + 1]);
      }
      out[60] = lp;
      out[61] = en;
    }
  }
}

extern "C" void kernel_launch(void* const* d_in, const int* in_sizes, int n_in,
                              void* d_out, int out_size, void* d_ws, size_t ws_size,
                              hipStream_t stream) {
  const float* enc = (const float*)d_in[0];
  const float* wih = (const float*)d_in[1];
  const float* whh = (const float*)d_in[2];
  const float* bih = (const float*)d_in[3];
  const float* bhh = (const float*)d_in[4];
  const float* w1  = (const float*)d_in[5];
  const float* w2  = (const float*)d_in[6];
  const float* v   = (const float*)d_in[7];
  unsigned char* ws = (unsigned char*)d_ws;
  float* out = (float*)d_out;

  ctrl_fused<<<dim3(64), dim3(1024), 0, stream>>>(
      enc, wih, whh, bih, bhh, w1, w2, v, ws, out);
}